// Round 4
// baseline (415.276 us; speedup 1.0000x reference)
//
#include <hip/hip_runtime.h>
#include <math.h>

#define N_NODES 100000
#define N_EDGES 1600000
#define D 64
#define LN_EPS 1e-5f
#define SCAN_NB 391       // ceil(100000/256)
#define NQ (N_EDGES / 4)  // 400000 quads

// ---- bf16 helpers (RNE) ----
__device__ __forceinline__ unsigned short f2b(float f) {
    unsigned u = __float_as_uint(f);
    return (unsigned short)((u + 0x7FFFu + ((u >> 16) & 1u)) >> 16);
}
__device__ __forceinline__ unsigned pk2(float lo, float hi) {
    return (unsigned)f2b(lo) | ((unsigned)f2b(hi) << 16);
}
__device__ __forceinline__ float b2f(unsigned short u) {
    return __uint_as_float((unsigned)u << 16);
}

// ---------------- f32 -> bf16 row conversion (8 elems/thread) ----------------
__global__ void k_tobf16(const float4* __restrict__ in4, uint4* __restrict__ out4) {
    int i = blockIdx.x * 256 + threadIdx.x;  // 3125*256 == N*D/8 exactly
    float4 a = in4[2 * i];
    float4 c = in4[2 * i + 1];
    uint4 o;
    o.x = pk2(a.x, a.y);
    o.y = pk2(a.z, a.w);
    o.z = pk2(c.x, c.y);
    o.w = pk2(c.z, c.w);
    out4[i] = o;
}

// ---------------- zero the per-node counters ----------------
__global__ void k_zero_counts(int* __restrict__ counts) {
    int i = blockIdx.x * 256 + threadIdx.x;
    if (i < N_NODES) counts[i] = 0;
}

// ---------------- histogram of dst (4 edges/thread) ----------------
__global__ void k_hist(const int4* __restrict__ dst4, int* __restrict__ counts) {
    int q = blockIdx.x * 256 + threadIdx.x;
    if (q < NQ) {
        int4 d = dst4[q];
        atomicAdd(&counts[d.x], 1);
        atomicAdd(&counts[d.y], 1);
        atomicAdd(&counts[d.z], 1);
        atomicAdd(&counts[d.w], 1);
    }
}

// ---------------- scan step 1: per-block exclusive scan + block sums ----------------
__global__ void k_scan1(const int* __restrict__ counts, int* __restrict__ offsets,
                        int* __restrict__ blockSums) {
    __shared__ int s[256];
    int tid = threadIdx.x;
    int i = blockIdx.x * 256 + tid;
    int v = (i < N_NODES) ? counts[i] : 0;
    s[tid] = v;
    __syncthreads();
    for (int off = 1; off < 256; off <<= 1) {
        int t = (tid >= off) ? s[tid - off] : 0;
        __syncthreads();
        s[tid] += t;
        __syncthreads();
    }
    if (i < N_NODES) offsets[i] = s[tid] - v;  // exclusive within block
    if (tid == 255) blockSums[blockIdx.x] = s[255];
}

// ---------------- scan step 2: exclusive scan of block sums (single block) ----------------
__global__ void k_scan2(int* __restrict__ blockSums) {
    __shared__ int s[512];
    int tid = threadIdx.x;
    int v = (tid < SCAN_NB) ? blockSums[tid] : 0;
    s[tid] = v;
    __syncthreads();
    for (int off = 1; off < 512; off <<= 1) {
        int t = (tid >= off) ? s[tid - off] : 0;
        __syncthreads();
        s[tid] += t;
        __syncthreads();
    }
    if (tid < SCAN_NB) blockSums[tid] = s[tid] - v;  // exclusive
}

// ---------------- scan step 3: add block offsets; init cursor ----------------
__global__ void k_scan3(int* __restrict__ offsets, const int* __restrict__ blockSums,
                        int* __restrict__ cursor) {
    int i = blockIdx.x * 256 + threadIdx.x;
    if (i < N_NODES) {
        int o = offsets[i] + blockSums[blockIdx.x];
        offsets[i] = o;
        cursor[i] = o;
    }
    if (i == 0) offsets[N_NODES] = N_EDGES;
}

// ---------------- bucket edges into CSR order: recA={src,adv0}, recB={src,adv1} ----------------
__global__ void k_bucket(const int4* __restrict__ src4, const int4* __restrict__ dst4,
                         const float4* __restrict__ adv04, const float4* __restrict__ adv14,
                         int* __restrict__ cursor, int2* __restrict__ recA,
                         int2* __restrict__ recB) {
    int q = blockIdx.x * 256 + threadIdx.x;
    if (q >= NQ) return;
    int4 s = src4[q];
    int4 d = dst4[q];
    float4 a0 = adv04[q];
    float4 a1 = adv14[q];
    int p;
    p = atomicAdd(&cursor[d.x], 1);
    recA[p] = make_int2(s.x, __float_as_int(a0.x));
    recB[p] = make_int2(s.x, __float_as_int(a1.x));
    p = atomicAdd(&cursor[d.y], 1);
    recA[p] = make_int2(s.y, __float_as_int(a0.y));
    recB[p] = make_int2(s.y, __float_as_int(a1.y));
    p = atomicAdd(&cursor[d.z], 1);
    recA[p] = make_int2(s.z, __float_as_int(a0.z));
    recB[p] = make_int2(s.z, __float_as_int(a1.z));
    p = atomicAdd(&cursor[d.w], 1);
    recA[p] = make_int2(s.w, __float_as_int(a0.w));
    recB[p] = make_int2(s.w, __float_as_int(a1.w));
}

// ---------------- fused layer: gather-aggregate(bf16) + gelu/res + matvec(LDS W) + LN ----------------
// LAYER==0: residual from xres(f32), output -> outb (bf16)
// LAYER==1: residual from xb(bf16), output -> outf (f32)
template <int LAYER>
__global__ __launch_bounds__(256) void k_layer(const float* __restrict__ xres,
                                               const unsigned short* __restrict__ xb,
                                               const long* __restrict__ rec,
                                               const int* __restrict__ offsets,
                                               const float* __restrict__ W,
                                               const float* __restrict__ bb,
                                               const float* __restrict__ gg,
                                               const float* __restrict__ be,
                                               float* __restrict__ outf,
                                               unsigned short* __restrict__ outb) {
    __shared__ float Wl[D * D];
    __shared__ float hs[4][D];
    for (int i = threadIdx.x; i < D * D; i += 256) Wl[i] = W[i];
    const int lane = threadIdx.x & 63;
    const int wid = threadIdx.x >> 6;
    const float bl = bb[lane], gl = gg[lane], bel = be[lane];
    __syncthreads();

    for (int grp = blockIdx.x; grp < N_NODES / 4; grp += gridDim.x) {
        const int node = grp * 4 + wid;
        const int beg = offsets[node];
        const int end = offsets[node + 1];

        float acc0 = 0.f, acc1 = 0.f, sadv = 0.f;
        for (int cb = beg; cb < end; cb += 64) {
            const int n = min(64, end - cb);
            long rl = 0;
            if (lane < n) rl = __builtin_nontemporal_load(rec + cb + lane);
            const int sv = (int)rl;            // src
            const int avi = (int)(rl >> 32);   // adv bits
            sadv += __int_as_float(avi);       // masked lanes add 0
            int k = 0;
            for (; k + 4 <= n; k += 4) {
                int s0 = __builtin_amdgcn_readlane(sv, k);
                int s1 = __builtin_amdgcn_readlane(sv, k + 1);
                int s2 = __builtin_amdgcn_readlane(sv, k + 2);
                int s3 = __builtin_amdgcn_readlane(sv, k + 3);
                float a0 = __int_as_float(__builtin_amdgcn_readlane(avi, k));
                float a1 = __int_as_float(__builtin_amdgcn_readlane(avi, k + 1));
                float a2 = __int_as_float(__builtin_amdgcn_readlane(avi, k + 2));
                float a3 = __int_as_float(__builtin_amdgcn_readlane(avi, k + 3));
                float x0 = b2f(xb[(unsigned)(s0 * D) + lane]);
                float x1 = b2f(xb[(unsigned)(s1 * D) + lane]);
                float x2 = b2f(xb[(unsigned)(s2 * D) + lane]);
                float x3 = b2f(xb[(unsigned)(s3 * D) + lane]);
                acc0 = fmaf(x0, a0, acc0);
                acc1 = fmaf(x1, a1, acc1);
                acc0 = fmaf(x2, a2, acc0);
                acc1 = fmaf(x3, a3, acc1);
            }
            for (; k < n; ++k) {
                int s0 = __builtin_amdgcn_readlane(sv, k);
                float a0 = __int_as_float(__builtin_amdgcn_readlane(avi, k));
                acc0 = fmaf(b2f(xb[(unsigned)(s0 * D) + lane]), a0, acc0);
            }
        }
        for (int m = 32; m; m >>= 1) sadv += __shfl_xor(sadv, m, 64);
        float aggr = (end > beg) ? (acc0 + acc1) / sadv : 0.f;

        float xv = (LAYER == 0) ? xres[(unsigned)(node * D) + lane]
                                : b2f(xb[(unsigned)(node * D) + lane]);
        // exact GELU: 0.5*a + 0.5*a*erf(a/sqrt(2)), plus residual
        float ge = 0.5f * aggr;
        float h = fmaf(ge, erff(aggr * 0.70710678118654752f), ge + xv);

        // wave-private LDS transpose; same-wave write/read needs no barrier
        hs[wid][lane] = h;
        float acc2 = bl;
        const float4* h4p = (const float4*)(&hs[wid][0]);
#pragma unroll
        for (int k4 = 0; k4 < 16; ++k4) {
            float4 h4 = h4p[k4];
            acc2 = fmaf(h4.x, Wl[(k4 * 4 + 0) * D + lane], acc2);
            acc2 = fmaf(h4.y, Wl[(k4 * 4 + 1) * D + lane], acc2);
            acc2 = fmaf(h4.z, Wl[(k4 * 4 + 2) * D + lane], acc2);
            acc2 = fmaf(h4.w, Wl[(k4 * 4 + 3) * D + lane], acc2);
        }

        // LayerNorm across the 64 lanes
        float s = acc2;
        for (int m = 32; m; m >>= 1) s += __shfl_xor(s, m, 64);
        float mu = s * (1.f / 64.f);
        float dv = acc2 - mu;
        float v2 = dv * dv;
        for (int m = 32; m; m >>= 1) v2 += __shfl_xor(v2, m, 64);
        float var = v2 * (1.f / 64.f);
        float res = dv * rsqrtf(var + LN_EPS) * gl + bel;

        if (LAYER == 0)
            outb[(unsigned)(node * D) + lane] = f2b(res);
        else
            __builtin_nontemporal_store(res, outf + (unsigned)(node * D) + lane);
    }
}

extern "C" void kernel_launch(void* const* d_in, const int* in_sizes, int n_in,
                              void* d_out, int out_size, void* d_ws, size_t ws_size,
                              hipStream_t stream) {
    const float* node_attr = (const float*)d_in[0];
    const int* edge_index = (const int*)d_in[1];
    // d_in[2] = batch_idx (unused)
    const float* adv0 = (const float*)d_in[3];
    const float* adv1 = (const float*)d_in[4];
    const float* W0 = (const float*)d_in[5];
    const float* b0 = (const float*)d_in[6];
    const float* g0 = (const float*)d_in[7];
    const float* be0 = (const float*)d_in[8];
    const float* W1 = (const float*)d_in[9];
    const float* b1 = (const float*)d_in[10];
    const float* g1 = (const float*)d_in[11];
    const float* be1 = (const float*)d_in[12];

    const int4* src4 = (const int4*)edge_index;              // edge_index[0]
    const int4* dst4 = (const int4*)(edge_index + N_EDGES);  // edge_index[1]
    const float4* adv04 = (const float4*)adv0;
    const float4* adv14 = (const float4*)adv1;

    // workspace layout (~52.4 MB)
    int2* recA = (int2*)d_ws;                                  // [E] 12.8 MB {src, adv0}
    int2* recB = recA + N_EDGES;                               // [E] 12.8 MB {src, adv1}
    unsigned short* xb0 = (unsigned short*)(recB + N_EDGES);   // [N*D] bf16 12.8 MB
    unsigned short* h1b = xb0 + (size_t)N_NODES * D;           // [N*D] bf16 12.8 MB
    int* offsets = (int*)(h1b + (size_t)N_NODES * D);          // [N+1]
    int* cursor = offsets + (N_NODES + 1);                     // [N]
    int* counts = cursor + N_NODES;                            // [N]
    int* blockSums = counts + N_NODES;                         // [512]

    float* out = (float*)d_out;

    // ---- node_attr -> bf16 (for the layer-1 gather) ----
    k_tobf16<<<3125, 256, 0, stream>>>((const float4*)node_attr, (uint4*)xb0);

    // ---- build CSR by dst (once; serves both layers) ----
    k_zero_counts<<<SCAN_NB, 256, 0, stream>>>(counts);
    k_hist<<<(NQ + 255) / 256, 256, 0, stream>>>(dst4, counts);
    k_scan1<<<SCAN_NB, 256, 0, stream>>>(counts, offsets, blockSums);
    k_scan2<<<1, 512, 0, stream>>>(blockSums);
    k_scan3<<<SCAN_NB, 256, 0, stream>>>(offsets, blockSums, cursor);
    k_bucket<<<(NQ + 255) / 256, 256, 0, stream>>>(src4, dst4, adv04, adv14, cursor,
                                                   recA, recB);

    // ---- layer 1: gather xb0, residual node_attr(f32) -> h1b (bf16) ----
    k_layer<0><<<2048, 256, 0, stream>>>(node_attr, xb0, (const long*)recA, offsets,
                                         W0, b0, g0, be0, nullptr, h1b);
    // ---- layer 2: gather h1b, residual h1b -> out (f32) ----
    k_layer<1><<<2048, 256, 0, stream>>>(nullptr, h1b, (const long*)recB, offsets,
                                         W1, b1, g1, be1, out, nullptr);
}

// Round 5
// 372.989 us; speedup vs baseline: 1.1134x; 1.1134x over previous
//
#include <hip/hip_runtime.h>
#include <math.h>

#define N_NODES 100000
#define N_EDGES 1600000
#define D 64
#define LN_EPS 1e-5f
#define SCAN_NB 391       // ceil(100000/256)
#define NQ (N_EDGES / 4)  // 400000 quads

// ---- bf16 helpers (RNE) ----
__device__ __forceinline__ unsigned short f2b(float f) {
    unsigned u = __float_as_uint(f);
    return (unsigned short)((u + 0x7FFFu + ((u >> 16) & 1u)) >> 16);
}
__device__ __forceinline__ unsigned pk2(float lo, float hi) {
    return (unsigned)f2b(lo) | ((unsigned)f2b(hi) << 16);
}
__device__ __forceinline__ float b2f(unsigned short u) {
    return __uint_as_float((unsigned)u << 16);
}

// ---------------- f32 -> bf16 row conversion (8 elems/thread) ----------------
__global__ void k_tobf16(const float4* __restrict__ in4, uint4* __restrict__ out4) {
    int i = blockIdx.x * 256 + threadIdx.x;  // 3125*256 == N*D/8 exactly
    float4 a = in4[2 * i];
    float4 c = in4[2 * i + 1];
    uint4 o;
    o.x = pk2(a.x, a.y);
    o.y = pk2(a.z, a.w);
    o.z = pk2(c.x, c.y);
    o.w = pk2(c.z, c.w);
    out4[i] = o;
}

// ---------------- zero the per-node counters ----------------
__global__ void k_zero_counts(int* __restrict__ counts) {
    int i = blockIdx.x * 256 + threadIdx.x;
    if (i < N_NODES) counts[i] = 0;
}

// ---------------- histogram of dst (4 edges/thread) ----------------
__global__ void k_hist(const int4* __restrict__ dst4, int* __restrict__ counts) {
    int q = blockIdx.x * 256 + threadIdx.x;
    if (q < NQ) {
        int4 d = dst4[q];
        atomicAdd(&counts[d.x], 1);
        atomicAdd(&counts[d.y], 1);
        atomicAdd(&counts[d.z], 1);
        atomicAdd(&counts[d.w], 1);
    }
}

// ---------------- scan step 1: per-block exclusive scan + block sums ----------------
__global__ void k_scan1(const int* __restrict__ counts, int* __restrict__ offsets,
                        int* __restrict__ blockSums) {
    __shared__ int s[256];
    int tid = threadIdx.x;
    int i = blockIdx.x * 256 + tid;
    int v = (i < N_NODES) ? counts[i] : 0;
    s[tid] = v;
    __syncthreads();
    for (int off = 1; off < 256; off <<= 1) {
        int t = (tid >= off) ? s[tid - off] : 0;
        __syncthreads();
        s[tid] += t;
        __syncthreads();
    }
    if (i < N_NODES) offsets[i] = s[tid] - v;  // exclusive within block
    if (tid == 255) blockSums[blockIdx.x] = s[255];
}

// ---------------- scan step 2: exclusive scan of block sums (single block) ----------------
__global__ void k_scan2(int* __restrict__ blockSums) {
    __shared__ int s[512];
    int tid = threadIdx.x;
    int v = (tid < SCAN_NB) ? blockSums[tid] : 0;
    s[tid] = v;
    __syncthreads();
    for (int off = 1; off < 512; off <<= 1) {
        int t = (tid >= off) ? s[tid - off] : 0;
        __syncthreads();
        s[tid] += t;
        __syncthreads();
    }
    if (tid < SCAN_NB) blockSums[tid] = s[tid] - v;  // exclusive
}

// ---------------- scan step 3: add block offsets; init cursor ----------------
__global__ void k_scan3(int* __restrict__ offsets, const int* __restrict__ blockSums,
                        int* __restrict__ cursor) {
    int i = blockIdx.x * 256 + threadIdx.x;
    if (i < N_NODES) {
        int o = offsets[i] + blockSums[blockIdx.x];
        offsets[i] = o;
        cursor[i] = o;
    }
    if (i == 0) offsets[N_NODES] = N_EDGES;
}

// ---------------- bucket edges into CSR order: recA={src,adv0}, recB={src,adv1} ----------------
__global__ void k_bucket(const int4* __restrict__ src4, const int4* __restrict__ dst4,
                         const float4* __restrict__ adv04, const float4* __restrict__ adv14,
                         int* __restrict__ cursor, int2* __restrict__ recA,
                         int2* __restrict__ recB) {
    int q = blockIdx.x * 256 + threadIdx.x;
    if (q >= NQ) return;
    int4 s = src4[q];
    int4 d = dst4[q];
    float4 a0 = adv04[q];
    float4 a1 = adv14[q];
    int p;
    p = atomicAdd(&cursor[d.x], 1);
    recA[p] = make_int2(s.x, __float_as_int(a0.x));
    recB[p] = make_int2(s.x, __float_as_int(a1.x));
    p = atomicAdd(&cursor[d.y], 1);
    recA[p] = make_int2(s.y, __float_as_int(a0.y));
    recB[p] = make_int2(s.y, __float_as_int(a1.y));
    p = atomicAdd(&cursor[d.z], 1);
    recA[p] = make_int2(s.z, __float_as_int(a0.z));
    recB[p] = make_int2(s.z, __float_as_int(a1.z));
    p = atomicAdd(&cursor[d.w], 1);
    recA[p] = make_int2(s.w, __float_as_int(a0.w));
    recB[p] = make_int2(s.w, __float_as_int(a1.w));
}

// ---------------- fused layer: gather-aggregate(bf16) + gelu/res + matvec + LN ----------------
// LAYER==0: residual from xres(f32), output -> outb (bf16)
// LAYER==1: residual from xb(bf16), output -> outf (f32)
template <int LAYER>
__global__ __launch_bounds__(256) void k_layer(const float* __restrict__ xres,
                                               const unsigned short* __restrict__ xb,
                                               const long* __restrict__ rec,
                                               const int* __restrict__ offsets,
                                               const float* __restrict__ W,
                                               const float* __restrict__ bb,
                                               const float* __restrict__ gg,
                                               const float* __restrict__ be,
                                               float* __restrict__ outf,
                                               unsigned short* __restrict__ outb) {
    const int lane = threadIdx.x & 63;
    const int wid = threadIdx.x >> 6;       // 4 waves/block, one node each
    const int node = blockIdx.x * 4 + wid;  // 25000*4 == N_NODES exactly
    const int beg = offsets[node];
    const int end = offsets[node + 1];

    float acc0 = 0.f, acc1 = 0.f, acc2a = 0.f, acc3a = 0.f, sadv = 0.f;
    for (int cb = beg; cb < end; cb += 64) {
        const int n = min(64, end - cb);
        long rl = 0;
        if (lane < n) rl = __builtin_nontemporal_load(rec + cb + lane);
        const int sv = (int)rl;           // src
        const int avi = (int)(rl >> 32);  // adv bits
        sadv += __int_as_float(avi);      // masked lanes add 0
        int k = 0;
        for (; k + 8 <= n; k += 8) {
            int s0 = __builtin_amdgcn_readlane(sv, k);
            int s1 = __builtin_amdgcn_readlane(sv, k + 1);
            int s2 = __builtin_amdgcn_readlane(sv, k + 2);
            int s3 = __builtin_amdgcn_readlane(sv, k + 3);
            int s4 = __builtin_amdgcn_readlane(sv, k + 4);
            int s5 = __builtin_amdgcn_readlane(sv, k + 5);
            int s6 = __builtin_amdgcn_readlane(sv, k + 6);
            int s7 = __builtin_amdgcn_readlane(sv, k + 7);
            float x0 = b2f(xb[(unsigned)(s0 * D) + lane]);
            float x1 = b2f(xb[(unsigned)(s1 * D) + lane]);
            float x2 = b2f(xb[(unsigned)(s2 * D) + lane]);
            float x3 = b2f(xb[(unsigned)(s3 * D) + lane]);
            float x4 = b2f(xb[(unsigned)(s4 * D) + lane]);
            float x5 = b2f(xb[(unsigned)(s5 * D) + lane]);
            float x6 = b2f(xb[(unsigned)(s6 * D) + lane]);
            float x7 = b2f(xb[(unsigned)(s7 * D) + lane]);
            float a0 = __int_as_float(__builtin_amdgcn_readlane(avi, k));
            float a1 = __int_as_float(__builtin_amdgcn_readlane(avi, k + 1));
            float a2 = __int_as_float(__builtin_amdgcn_readlane(avi, k + 2));
            float a3 = __int_as_float(__builtin_amdgcn_readlane(avi, k + 3));
            float a4 = __int_as_float(__builtin_amdgcn_readlane(avi, k + 4));
            float a5 = __int_as_float(__builtin_amdgcn_readlane(avi, k + 5));
            float a6 = __int_as_float(__builtin_amdgcn_readlane(avi, k + 6));
            float a7 = __int_as_float(__builtin_amdgcn_readlane(avi, k + 7));
            acc0 = fmaf(x0, a0, acc0);
            acc1 = fmaf(x1, a1, acc1);
            acc2a = fmaf(x2, a2, acc2a);
            acc3a = fmaf(x3, a3, acc3a);
            acc0 = fmaf(x4, a4, acc0);
            acc1 = fmaf(x5, a5, acc1);
            acc2a = fmaf(x6, a6, acc2a);
            acc3a = fmaf(x7, a7, acc3a);
        }
        for (; k + 4 <= n; k += 4) {
            int s0 = __builtin_amdgcn_readlane(sv, k);
            int s1 = __builtin_amdgcn_readlane(sv, k + 1);
            int s2 = __builtin_amdgcn_readlane(sv, k + 2);
            int s3 = __builtin_amdgcn_readlane(sv, k + 3);
            float x0 = b2f(xb[(unsigned)(s0 * D) + lane]);
            float x1 = b2f(xb[(unsigned)(s1 * D) + lane]);
            float x2 = b2f(xb[(unsigned)(s2 * D) + lane]);
            float x3 = b2f(xb[(unsigned)(s3 * D) + lane]);
            float a0 = __int_as_float(__builtin_amdgcn_readlane(avi, k));
            float a1 = __int_as_float(__builtin_amdgcn_readlane(avi, k + 1));
            float a2 = __int_as_float(__builtin_amdgcn_readlane(avi, k + 2));
            float a3 = __int_as_float(__builtin_amdgcn_readlane(avi, k + 3));
            acc0 = fmaf(x0, a0, acc0);
            acc1 = fmaf(x1, a1, acc1);
            acc2a = fmaf(x2, a2, acc2a);
            acc3a = fmaf(x3, a3, acc3a);
        }
        for (; k < n; ++k) {
            int s0 = __builtin_amdgcn_readlane(sv, k);
            float a0 = __int_as_float(__builtin_amdgcn_readlane(avi, k));
            acc0 = fmaf(b2f(xb[(unsigned)(s0 * D) + lane]), a0, acc0);
        }
    }
    for (int m = 32; m; m >>= 1) sadv += __shfl_xor(sadv, m, 64);
    float acc = (acc0 + acc1) + (acc2a + acc3a);
    float aggr = (end > beg) ? acc / sadv : 0.f;

    float xv = (LAYER == 0) ? xres[(unsigned)(node * D) + lane]
                            : b2f(xb[(unsigned)(node * D) + lane]);
    // exact GELU: 0.5*a + 0.5*a*erf(a/sqrt(2)), plus residual
    float ge = 0.5f * aggr;
    float h = fmaf(ge, erff(aggr * 0.70710678118654752f), ge + xv);

    // wave-private LDS transpose; same-wave write/read (no barrier needed)
    __shared__ float hs[4][D];
    hs[wid][lane] = h;
    float acc2 = bb[lane];
    const float4* h4p = (const float4*)(&hs[wid][0]);
#pragma unroll
    for (int k4 = 0; k4 < 16; ++k4) {
        float4 h4 = h4p[k4];
        acc2 = fmaf(h4.x, W[(k4 * 4 + 0) * D + lane], acc2);
        acc2 = fmaf(h4.y, W[(k4 * 4 + 1) * D + lane], acc2);
        acc2 = fmaf(h4.z, W[(k4 * 4 + 2) * D + lane], acc2);
        acc2 = fmaf(h4.w, W[(k4 * 4 + 3) * D + lane], acc2);
    }

    // LayerNorm across the 64 lanes
    float s = acc2;
    for (int m = 32; m; m >>= 1) s += __shfl_xor(s, m, 64);
    float mu = s * (1.f / 64.f);
    float dv = acc2 - mu;
    float v2 = dv * dv;
    for (int m = 32; m; m >>= 1) v2 += __shfl_xor(v2, m, 64);
    float var = v2 * (1.f / 64.f);
    float res = dv * rsqrtf(var + LN_EPS) * gg[lane] + be[lane];

    if (LAYER == 0)
        outb[(unsigned)(node * D) + lane] = f2b(res);
    else
        __builtin_nontemporal_store(res, outf + (unsigned)(node * D) + lane);
}

extern "C" void kernel_launch(void* const* d_in, const int* in_sizes, int n_in,
                              void* d_out, int out_size, void* d_ws, size_t ws_size,
                              hipStream_t stream) {
    const float* node_attr = (const float*)d_in[0];
    const int* edge_index = (const int*)d_in[1];
    // d_in[2] = batch_idx (unused)
    const float* adv0 = (const float*)d_in[3];
    const float* adv1 = (const float*)d_in[4];
    const float* W0 = (const float*)d_in[5];
    const float* b0 = (const float*)d_in[6];
    const float* g0 = (const float*)d_in[7];
    const float* be0 = (const float*)d_in[8];
    const float* W1 = (const float*)d_in[9];
    const float* b1 = (const float*)d_in[10];
    const float* g1 = (const float*)d_in[11];
    const float* be1 = (const float*)d_in[12];

    const int4* src4 = (const int4*)edge_index;              // edge_index[0]
    const int4* dst4 = (const int4*)(edge_index + N_EDGES);  // edge_index[1]
    const float4* adv04 = (const float4*)adv0;
    const float4* adv14 = (const float4*)adv1;

    // workspace layout (~52 MB)
    int2* recA = (int2*)d_ws;                                 // [E] 12.8 MB {src, adv0}
    int2* recB = recA + N_EDGES;                              // [E] 12.8 MB {src, adv1}
    unsigned short* xb0 = (unsigned short*)(recB + N_EDGES);  // [N*D] bf16 12.8 MB
    unsigned short* h1b = xb0 + (size_t)N_NODES * D;          // [N*D] bf16 12.8 MB
    int* offsets = (int*)(h1b + (size_t)N_NODES * D);         // [N+1]
    int* cursor = offsets + (N_NODES + 1);                    // [N]
    int* counts = cursor + N_NODES;                           // [N]
    int* blockSums = counts + N_NODES;                        // [512]

    float* out = (float*)d_out;

    // ---- node_attr -> bf16 (for the layer-1 gather) ----
    k_tobf16<<<3125, 256, 0, stream>>>((const float4*)node_attr, (uint4*)xb0);

    // ---- build CSR by dst (once; serves both layers) ----
    k_zero_counts<<<SCAN_NB, 256, 0, stream>>>(counts);
    k_hist<<<(NQ + 255) / 256, 256, 0, stream>>>(dst4, counts);
    k_scan1<<<SCAN_NB, 256, 0, stream>>>(counts, offsets, blockSums);
    k_scan2<<<1, 512, 0, stream>>>(blockSums);
    k_scan3<<<SCAN_NB, 256, 0, stream>>>(offsets, blockSums, cursor);
    k_bucket<<<(NQ + 255) / 256, 256, 0, stream>>>(src4, dst4, adv04, adv14, cursor,
                                                   recA, recB);

    // ---- layer 1: gather xb0, residual node_attr(f32) -> h1b (bf16) ----
    k_layer<0><<<N_NODES / 4, 256, 0, stream>>>(node_attr, xb0, (const long*)recA, offsets,
                                                W0, b0, g0, be0, nullptr, h1b);
    // ---- layer 2: gather h1b, residual h1b -> out (f32) ----
    k_layer<1><<<N_NODES / 4, 256, 0, stream>>>(nullptr, h1b, (const long*)recB, offsets,
                                                W1, b1, g1, be1, out, nullptr);
}

// Round 7
// 367.411 us; speedup vs baseline: 1.1303x; 1.0152x over previous
//
#include <hip/hip_runtime.h>
#include <math.h>

#define N_NODES 100000
#define N_EDGES 1600000
#define D 64
#define LN_EPS 1e-5f
#define SCAN_NB 391  // ceil(100000/256)

typedef int v4i __attribute__((ext_vector_type(4)));

// ---- bf16 helpers (RNE) ----
__device__ __forceinline__ unsigned short f2b(float f) {
    unsigned u = __float_as_uint(f);
    return (unsigned short)((u + 0x7FFFu + ((u >> 16) & 1u)) >> 16);
}
__device__ __forceinline__ unsigned pk2(float lo, float hi) {
    return (unsigned)f2b(lo) | ((unsigned)f2b(hi) << 16);
}
__device__ __forceinline__ float b2f(unsigned short u) {
    return __uint_as_float((unsigned)u << 16);
}

// ---------------- f32 -> bf16 row conversion (8 elems/thread) + zero counts ----------------
__global__ void k_tobf16z(const float4* __restrict__ in4, uint4* __restrict__ out4,
                          int* __restrict__ counts) {
    int i = blockIdx.x * 256 + threadIdx.x;  // 3125*256 == N*D/8 exactly
    if (i < N_NODES) counts[i] = 0;
    float4 a = in4[2 * i];
    float4 c = in4[2 * i + 1];
    uint4 o;
    o.x = pk2(a.x, a.y);
    o.y = pk2(a.z, a.w);
    o.z = pk2(c.x, c.y);
    o.w = pk2(c.z, c.w);
    out4[i] = o;
}

// ---------------- histogram of dst (1 edge/thread) ----------------
__global__ void k_hist(const int* __restrict__ dst, int* __restrict__ counts) {
    int e = blockIdx.x * 256 + threadIdx.x;  // 6250*256 == N_EDGES exactly
    atomicAdd(&counts[dst[e]], 1);
}

// ---------------- scan step 1: per-block exclusive scan + block sums ----------------
__global__ void k_scan1(const int* __restrict__ counts, int* __restrict__ offsets,
                        int* __restrict__ blockSums) {
    __shared__ int s[256];
    int tid = threadIdx.x;
    int i = blockIdx.x * 256 + tid;
    int v = (i < N_NODES) ? counts[i] : 0;
    s[tid] = v;
    __syncthreads();
    for (int off = 1; off < 256; off <<= 1) {
        int t = (tid >= off) ? s[tid - off] : 0;
        __syncthreads();
        s[tid] += t;
        __syncthreads();
    }
    if (i < N_NODES) offsets[i] = s[tid] - v;  // exclusive within block
    if (tid == 255) blockSums[blockIdx.x] = s[255];
}

// ---------------- scan step 2: exclusive scan of block sums (single block) ----------------
__global__ void k_scan2(int* __restrict__ blockSums) {
    __shared__ int s[512];
    int tid = threadIdx.x;
    int v = (tid < SCAN_NB) ? blockSums[tid] : 0;
    s[tid] = v;
    __syncthreads();
    for (int off = 1; off < 512; off <<= 1) {
        int t = (tid >= off) ? s[tid - off] : 0;
        __syncthreads();
        s[tid] += t;
        __syncthreads();
    }
    if (tid < SCAN_NB) blockSums[tid] = s[tid] - v;  // exclusive
}

// ---------------- scan step 3: add block offsets; init cursor ----------------
__global__ void k_scan3(int* __restrict__ offsets, const int* __restrict__ blockSums,
                        int* __restrict__ cursor) {
    int i = blockIdx.x * 256 + threadIdx.x;
    if (i < N_NODES) {
        int o = offsets[i] + blockSums[blockIdx.x];
        offsets[i] = o;
        cursor[i] = o;
    }
    if (i == 0) offsets[N_NODES] = N_EDGES;
}

// ---------------- bucket edges into CSR order: rec={src,adv0,adv1,0} (1 edge/thread) ----------------
__global__ void k_bucket(const int* __restrict__ src, const int* __restrict__ dst,
                         const float* __restrict__ adv0, const float* __restrict__ adv1,
                         int* __restrict__ cursor, v4i* __restrict__ rec) {
    int e = blockIdx.x * 256 + threadIdx.x;  // exact
    int s = src[e];
    int d = dst[e];
    float a0 = adv0[e];
    float a1 = adv1[e];
    int p = atomicAdd(&cursor[d], 1);
    v4i r;
    r.x = s;
    r.y = __float_as_int(a0);
    r.z = __float_as_int(a1);
    r.w = 0;
    rec[p] = r;
}

// ---------------- fused layer: gather-aggregate(bf16) + gelu/res + matvec + LN ----------------
// LAYER==0: residual from xres(f32), adv=rec.y, output -> outb (bf16)
// LAYER==1: residual from xb(bf16),  adv=rec.z, output -> outf (f32)
template <int LAYER>
__global__ __launch_bounds__(256) void k_layer(const float* __restrict__ xres,
                                               const unsigned short* __restrict__ xb,
                                               const v4i* __restrict__ rec,
                                               const int* __restrict__ offsets,
                                               const float* __restrict__ W,
                                               const float* __restrict__ bb,
                                               const float* __restrict__ gg,
                                               const float* __restrict__ be,
                                               float* __restrict__ outf,
                                               unsigned short* __restrict__ outb) {
    const int lane = threadIdx.x & 63;
    const int wid = threadIdx.x >> 6;       // 4 waves/block, one node each
    const int node = blockIdx.x * 4 + wid;  // 25000*4 == N_NODES exactly
    const int beg = offsets[node];
    const int end = offsets[node + 1];

    float acc0 = 0.f, acc1 = 0.f, acc2a = 0.f, acc3a = 0.f, sadv = 0.f;
    for (int cb = beg; cb < end; cb += 64) {
        const int n = min(64, end - cb);
        int sv = 0, avi = 0;
        if (lane < n) {
            v4i r = __builtin_nontemporal_load(rec + cb + lane);
            sv = r.x;
            avi = LAYER ? r.z : r.y;
        }
        sadv += __int_as_float(avi);  // masked lanes add 0
        int k = 0;
        for (; k + 8 <= n; k += 8) {
            int s0 = __builtin_amdgcn_readlane(sv, k);
            int s1 = __builtin_amdgcn_readlane(sv, k + 1);
            int s2 = __builtin_amdgcn_readlane(sv, k + 2);
            int s3 = __builtin_amdgcn_readlane(sv, k + 3);
            int s4 = __builtin_amdgcn_readlane(sv, k + 4);
            int s5 = __builtin_amdgcn_readlane(sv, k + 5);
            int s6 = __builtin_amdgcn_readlane(sv, k + 6);
            int s7 = __builtin_amdgcn_readlane(sv, k + 7);
            float x0 = b2f(xb[(unsigned)(s0 * D) + lane]);
            float x1 = b2f(xb[(unsigned)(s1 * D) + lane]);
            float x2 = b2f(xb[(unsigned)(s2 * D) + lane]);
            float x3 = b2f(xb[(unsigned)(s3 * D) + lane]);
            float x4 = b2f(xb[(unsigned)(s4 * D) + lane]);
            float x5 = b2f(xb[(unsigned)(s5 * D) + lane]);
            float x6 = b2f(xb[(unsigned)(s6 * D) + lane]);
            float x7 = b2f(xb[(unsigned)(s7 * D) + lane]);
            float a0 = __int_as_float(__builtin_amdgcn_readlane(avi, k));
            float a1 = __int_as_float(__builtin_amdgcn_readlane(avi, k + 1));
            float a2 = __int_as_float(__builtin_amdgcn_readlane(avi, k + 2));
            float a3 = __int_as_float(__builtin_amdgcn_readlane(avi, k + 3));
            float a4 = __int_as_float(__builtin_amdgcn_readlane(avi, k + 4));
            float a5 = __int_as_float(__builtin_amdgcn_readlane(avi, k + 5));
            float a6 = __int_as_float(__builtin_amdgcn_readlane(avi, k + 6));
            float a7 = __int_as_float(__builtin_amdgcn_readlane(avi, k + 7));
            acc0 = fmaf(x0, a0, acc0);
            acc1 = fmaf(x1, a1, acc1);
            acc2a = fmaf(x2, a2, acc2a);
            acc3a = fmaf(x3, a3, acc3a);
            acc0 = fmaf(x4, a4, acc0);
            acc1 = fmaf(x5, a5, acc1);
            acc2a = fmaf(x6, a6, acc2a);
            acc3a = fmaf(x7, a7, acc3a);
        }
        for (; k + 4 <= n; k += 4) {
            int s0 = __builtin_amdgcn_readlane(sv, k);
            int s1 = __builtin_amdgcn_readlane(sv, k + 1);
            int s2 = __builtin_amdgcn_readlane(sv, k + 2);
            int s3 = __builtin_amdgcn_readlane(sv, k + 3);
            float x0 = b2f(xb[(unsigned)(s0 * D) + lane]);
            float x1 = b2f(xb[(unsigned)(s1 * D) + lane]);
            float x2 = b2f(xb[(unsigned)(s2 * D) + lane]);
            float x3 = b2f(xb[(unsigned)(s3 * D) + lane]);
            float a0 = __int_as_float(__builtin_amdgcn_readlane(avi, k));
            float a1 = __int_as_float(__builtin_amdgcn_readlane(avi, k + 1));
            float a2 = __int_as_float(__builtin_amdgcn_readlane(avi, k + 2));
            float a3 = __int_as_float(__builtin_amdgcn_readlane(avi, k + 3));
            acc0 = fmaf(x0, a0, acc0);
            acc1 = fmaf(x1, a1, acc1);
            acc2a = fmaf(x2, a2, acc2a);
            acc3a = fmaf(x3, a3, acc3a);
        }
        for (; k < n; ++k) {
            int s0 = __builtin_amdgcn_readlane(sv, k);
            float a0 = __int_as_float(__builtin_amdgcn_readlane(avi, k));
            acc0 = fmaf(b2f(xb[(unsigned)(s0 * D) + lane]), a0, acc0);
        }
    }
    for (int m = 32; m; m >>= 1) sadv += __shfl_xor(sadv, m, 64);
    float acc = (acc0 + acc1) + (acc2a + acc3a);
    float aggr = (end > beg) ? acc / sadv : 0.f;

    float xv = (LAYER == 0) ? xres[(unsigned)(node * D) + lane]
                            : b2f(xb[(unsigned)(node * D) + lane]);
    // exact GELU: 0.5*a + 0.5*a*erf(a/sqrt(2)), plus residual
    float ge = 0.5f * aggr;
    float h = fmaf(ge, erff(aggr * 0.70710678118654752f), ge + xv);

    // wave-private LDS transpose; same-wave write/read (no barrier needed)
    __shared__ float hs[4][D];
    hs[wid][lane] = h;
    float acc2 = bb[lane];
    const float4* h4p = (const float4*)(&hs[wid][0]);
#pragma unroll
    for (int k4 = 0; k4 < 16; ++k4) {
        float4 h4 = h4p[k4];
        acc2 = fmaf(h4.x, W[(k4 * 4 + 0) * D + lane], acc2);
        acc2 = fmaf(h4.y, W[(k4 * 4 + 1) * D + lane], acc2);
        acc2 = fmaf(h4.z, W[(k4 * 4 + 2) * D + lane], acc2);
        acc2 = fmaf(h4.w, W[(k4 * 4 + 3) * D + lane], acc2);
    }

    // LayerNorm across the 64 lanes
    float s = acc2;
    for (int m = 32; m; m >>= 1) s += __shfl_xor(s, m, 64);
    float mu = s * (1.f / 64.f);
    float dv = acc2 - mu;
    float v2 = dv * dv;
    for (int m = 32; m; m >>= 1) v2 += __shfl_xor(v2, m, 64);
    float var = v2 * (1.f / 64.f);
    float res = dv * rsqrtf(var + LN_EPS) * gg[lane] + be[lane];

    if (LAYER == 0)
        outb[(unsigned)(node * D) + lane] = f2b(res);
    else
        __builtin_nontemporal_store(res, outf + (unsigned)(node * D) + lane);
}

extern "C" void kernel_launch(void* const* d_in, const int* in_sizes, int n_in,
                              void* d_out, int out_size, void* d_ws, size_t ws_size,
                              hipStream_t stream) {
    const float* node_attr = (const float*)d_in[0];
    const int* edge_index = (const int*)d_in[1];
    // d_in[2] = batch_idx (unused)
    const float* adv0 = (const float*)d_in[3];
    const float* adv1 = (const float*)d_in[4];
    const float* W0 = (const float*)d_in[5];
    const float* b0 = (const float*)d_in[6];
    const float* g0 = (const float*)d_in[7];
    const float* be0 = (const float*)d_in[8];
    const float* W1 = (const float*)d_in[9];
    const float* b1 = (const float*)d_in[10];
    const float* g1 = (const float*)d_in[11];
    const float* be1 = (const float*)d_in[12];

    const int* src = edge_index;            // edge_index[0]
    const int* dst = edge_index + N_EDGES;  // edge_index[1]

    // workspace layout (~52 MB)
    v4i* rec = (v4i*)d_ws;                                      // [E] 25.6 MB {src,adv0,adv1,0}
    unsigned short* xb0 = (unsigned short*)(rec + N_EDGES);     // [N*D] bf16 12.8 MB
    unsigned short* h1b = xb0 + (size_t)N_NODES * D;            // [N*D] bf16 12.8 MB
    int* offsets = (int*)(h1b + (size_t)N_NODES * D);           // [N+1]
    int* cursor = offsets + (N_NODES + 1);                      // [N]
    int* counts = cursor + N_NODES;                             // [N]
    int* blockSums = counts + N_NODES;                          // [512]

    float* out = (float*)d_out;

    // ---- node_attr -> bf16 + zero counts ----
    k_tobf16z<<<3125, 256, 0, stream>>>((const float4*)node_attr, (uint4*)xb0, counts);

    // ---- build CSR by dst (once; serves both layers) ----
    k_hist<<<N_EDGES / 256, 256, 0, stream>>>(dst, counts);
    k_scan1<<<SCAN_NB, 256, 0, stream>>>(counts, offsets, blockSums);
    k_scan2<<<1, 512, 0, stream>>>(blockSums);
    k_scan3<<<SCAN_NB, 256, 0, stream>>>(offsets, blockSums, cursor);
    k_bucket<<<N_EDGES / 256, 256, 0, stream>>>(src, dst, adv0, adv1, cursor, rec);

    // ---- layer 1: gather xb0, residual node_attr(f32) -> h1b (bf16) ----
    k_layer<0><<<N_NODES / 4, 256, 0, stream>>>(node_attr, xb0, rec, offsets,
                                                W0, b0, g0, be0, nullptr, h1b);
    // ---- layer 2: gather h1b, residual h1b -> out (f32) ----
    k_layer<1><<<N_NODES / 4, 256, 0, stream>>>(nullptr, h1b, rec, offsets,
                                                W1, b1, g1, be1, out, nullptr);
}

// Round 8
// 362.740 us; speedup vs baseline: 1.1448x; 1.0129x over previous
//
#include <hip/hip_runtime.h>
#include <math.h>

#define N_NODES 100000
#define N_EDGES 1600000
#define D 64
#define LN_EPS 1e-5f
#define SCAN_NB 391  // ceil(100000/256)

typedef int v2i __attribute__((ext_vector_type(2)));

// ---- bf16 helpers (RNE) ----
__device__ __forceinline__ unsigned short f2b(float f) {
    unsigned u = __float_as_uint(f);
    return (unsigned short)((u + 0x7FFFu + ((u >> 16) & 1u)) >> 16);
}
__device__ __forceinline__ unsigned pk2(float lo, float hi) {
    return (unsigned)f2b(lo) | ((unsigned)f2b(hi) << 16);
}
__device__ __forceinline__ float b2f(unsigned short u) {
    return __uint_as_float((unsigned)u << 16);
}

// ---------------- f32 -> bf16 row conversion (8 elems/thread) + zero counts ----------------
__global__ void k_tobf16z(const float4* __restrict__ in4, uint4* __restrict__ out4,
                          int* __restrict__ counts) {
    int i = blockIdx.x * 256 + threadIdx.x;  // 3125*256 == N*D/8 exactly
    if (i < N_NODES) counts[i] = 0;
    float4 a = in4[2 * i];
    float4 c = in4[2 * i + 1];
    uint4 o;
    o.x = pk2(a.x, a.y);
    o.y = pk2(a.z, a.w);
    o.z = pk2(c.x, c.y);
    o.w = pk2(c.z, c.w);
    out4[i] = o;
}

// ---------------- histogram of dst (1 edge/thread) ----------------
__global__ void k_hist(const int* __restrict__ dst, int* __restrict__ counts) {
    int e = blockIdx.x * 256 + threadIdx.x;  // 6250*256 == N_EDGES exactly
    atomicAdd(&counts[dst[e]], 1);
}

// ---------------- scan step 1: per-block exclusive scan + block sums ----------------
__global__ void k_scan1(const int* __restrict__ counts, int* __restrict__ offsets,
                        int* __restrict__ blockSums) {
    __shared__ int s[256];
    int tid = threadIdx.x;
    int i = blockIdx.x * 256 + tid;
    int v = (i < N_NODES) ? counts[i] : 0;
    s[tid] = v;
    __syncthreads();
    for (int off = 1; off < 256; off <<= 1) {
        int t = (tid >= off) ? s[tid - off] : 0;
        __syncthreads();
        s[tid] += t;
        __syncthreads();
    }
    if (i < N_NODES) offsets[i] = s[tid] - v;  // exclusive within block
    if (tid == 255) blockSums[blockIdx.x] = s[255];
}

// ---------------- scan step 2: exclusive scan of block sums (single block) ----------------
__global__ void k_scan2(int* __restrict__ blockSums) {
    __shared__ int s[512];
    int tid = threadIdx.x;
    int v = (tid < SCAN_NB) ? blockSums[tid] : 0;
    s[tid] = v;
    __syncthreads();
    for (int off = 1; off < 512; off <<= 1) {
        int t = (tid >= off) ? s[tid - off] : 0;
        __syncthreads();
        s[tid] += t;
        __syncthreads();
    }
    if (tid < SCAN_NB) blockSums[tid] = s[tid] - v;  // exclusive
}

// ---------------- scan step 3: add block offsets; init cursor ----------------
__global__ void k_scan3(int* __restrict__ offsets, const int* __restrict__ blockSums,
                        int* __restrict__ cursor) {
    int i = blockIdx.x * 256 + threadIdx.x;
    if (i < N_NODES) {
        int o = offsets[i] + blockSums[blockIdx.x];
        offsets[i] = o;
        cursor[i] = o;
    }
    if (i == 0) offsets[N_NODES] = N_EDGES;
}

// ---------------- bucket edges into CSR order: rec={src, bf16(adv0)|bf16(adv1)<<16} ----------------
__global__ void k_bucket(const int* __restrict__ src, const int* __restrict__ dst,
                         const float* __restrict__ adv0, const float* __restrict__ adv1,
                         int* __restrict__ cursor, v2i* __restrict__ rec) {
    int e = blockIdx.x * 256 + threadIdx.x;  // exact
    int s = src[e];
    int d = dst[e];
    float a0 = adv0[e];
    float a1 = adv1[e];
    int p = atomicAdd(&cursor[d], 1);
    v2i r;
    r.x = s;
    r.y = (int)pk2(a0, a1);
    rec[p] = r;
}

// ---------------- fused layer: gather-aggregate(bf16) + gelu/res + matvec + LN ----------------
// LAYER==0: residual from xres(f32), adv=lo16(rec.y), output -> outb (bf16)
// LAYER==1: residual from xb(bf16),  adv=hi16(rec.y), output -> outf (f32)
template <int LAYER>
__global__ __launch_bounds__(256) void k_layer(const float* __restrict__ xres,
                                               const unsigned short* __restrict__ xb,
                                               const v2i* __restrict__ rec,
                                               const int* __restrict__ offsets,
                                               const float* __restrict__ W,
                                               const float* __restrict__ bb,
                                               const float* __restrict__ gg,
                                               const float* __restrict__ be,
                                               float* __restrict__ outf,
                                               unsigned short* __restrict__ outb) {
    const int lane = threadIdx.x & 63;
    const int wid = threadIdx.x >> 6;       // 4 waves/block, one node each
    const int node = blockIdx.x * 4 + wid;  // 25000*4 == N_NODES exactly
    const int beg = offsets[node];
    const int end = offsets[node + 1];

    float acc0 = 0.f, acc1 = 0.f, acc2a = 0.f, acc3a = 0.f, sadv = 0.f;
    for (int cb = beg; cb < end; cb += 64) {
        const int n = min(64, end - cb);
        int sv = 0, avi = 0;
        if (lane < n) {
            v2i r = __builtin_nontemporal_load(rec + cb + lane);
            sv = r.x;
            unsigned pa = (unsigned)r.y;
            avi = (int)(LAYER ? (pa & 0xFFFF0000u) : (pa << 16));  // f32 bits of adv
        }
        sadv += __int_as_float(avi);  // masked lanes add 0
        int k = 0;
        for (; k + 8 <= n; k += 8) {
            int s0 = __builtin_amdgcn_readlane(sv, k);
            int s1 = __builtin_amdgcn_readlane(sv, k + 1);
            int s2 = __builtin_amdgcn_readlane(sv, k + 2);
            int s3 = __builtin_amdgcn_readlane(sv, k + 3);
            int s4 = __builtin_amdgcn_readlane(sv, k + 4);
            int s5 = __builtin_amdgcn_readlane(sv, k + 5);
            int s6 = __builtin_amdgcn_readlane(sv, k + 6);
            int s7 = __builtin_amdgcn_readlane(sv, k + 7);
            float x0 = b2f(xb[(unsigned)(s0 * D) + lane]);
            float x1 = b2f(xb[(unsigned)(s1 * D) + lane]);
            float x2 = b2f(xb[(unsigned)(s2 * D) + lane]);
            float x3 = b2f(xb[(unsigned)(s3 * D) + lane]);
            float x4 = b2f(xb[(unsigned)(s4 * D) + lane]);
            float x5 = b2f(xb[(unsigned)(s5 * D) + lane]);
            float x6 = b2f(xb[(unsigned)(s6 * D) + lane]);
            float x7 = b2f(xb[(unsigned)(s7 * D) + lane]);
            float a0 = __int_as_float(__builtin_amdgcn_readlane(avi, k));
            float a1 = __int_as_float(__builtin_amdgcn_readlane(avi, k + 1));
            float a2 = __int_as_float(__builtin_amdgcn_readlane(avi, k + 2));
            float a3 = __int_as_float(__builtin_amdgcn_readlane(avi, k + 3));
            float a4 = __int_as_float(__builtin_amdgcn_readlane(avi, k + 4));
            float a5 = __int_as_float(__builtin_amdgcn_readlane(avi, k + 5));
            float a6 = __int_as_float(__builtin_amdgcn_readlane(avi, k + 6));
            float a7 = __int_as_float(__builtin_amdgcn_readlane(avi, k + 7));
            acc0 = fmaf(x0, a0, acc0);
            acc1 = fmaf(x1, a1, acc1);
            acc2a = fmaf(x2, a2, acc2a);
            acc3a = fmaf(x3, a3, acc3a);
            acc0 = fmaf(x4, a4, acc0);
            acc1 = fmaf(x5, a5, acc1);
            acc2a = fmaf(x6, a6, acc2a);
            acc3a = fmaf(x7, a7, acc3a);
        }
        for (; k + 4 <= n; k += 4) {
            int s0 = __builtin_amdgcn_readlane(sv, k);
            int s1 = __builtin_amdgcn_readlane(sv, k + 1);
            int s2 = __builtin_amdgcn_readlane(sv, k + 2);
            int s3 = __builtin_amdgcn_readlane(sv, k + 3);
            float x0 = b2f(xb[(unsigned)(s0 * D) + lane]);
            float x1 = b2f(xb[(unsigned)(s1 * D) + lane]);
            float x2 = b2f(xb[(unsigned)(s2 * D) + lane]);
            float x3 = b2f(xb[(unsigned)(s3 * D) + lane]);
            float a0 = __int_as_float(__builtin_amdgcn_readlane(avi, k));
            float a1 = __int_as_float(__builtin_amdgcn_readlane(avi, k + 1));
            float a2 = __int_as_float(__builtin_amdgcn_readlane(avi, k + 2));
            float a3 = __int_as_float(__builtin_amdgcn_readlane(avi, k + 3));
            acc0 = fmaf(x0, a0, acc0);
            acc1 = fmaf(x1, a1, acc1);
            acc2a = fmaf(x2, a2, acc2a);
            acc3a = fmaf(x3, a3, acc3a);
        }
        for (; k < n; ++k) {
            int s0 = __builtin_amdgcn_readlane(sv, k);
            float a0 = __int_as_float(__builtin_amdgcn_readlane(avi, k));
            acc0 = fmaf(b2f(xb[(unsigned)(s0 * D) + lane]), a0, acc0);
        }
    }
    for (int m = 32; m; m >>= 1) sadv += __shfl_xor(sadv, m, 64);
    float acc = (acc0 + acc1) + (acc2a + acc3a);
    float aggr = (end > beg) ? acc / sadv : 0.f;

    float xv = (LAYER == 0) ? xres[(unsigned)(node * D) + lane]
                            : b2f(xb[(unsigned)(node * D) + lane]);
    // exact GELU: 0.5*a + 0.5*a*erf(a/sqrt(2)), plus residual
    float ge = 0.5f * aggr;
    float h = fmaf(ge, erff(aggr * 0.70710678118654752f), ge + xv);

    // wave-private LDS transpose; same-wave write/read (no barrier needed)
    __shared__ float hs[4][D];
    hs[wid][lane] = h;
    float acc2 = bb[lane];
    const float4* h4p = (const float4*)(&hs[wid][0]);
#pragma unroll
    for (int k4 = 0; k4 < 16; ++k4) {
        float4 h4 = h4p[k4];
        acc2 = fmaf(h4.x, W[(k4 * 4 + 0) * D + lane], acc2);
        acc2 = fmaf(h4.y, W[(k4 * 4 + 1) * D + lane], acc2);
        acc2 = fmaf(h4.z, W[(k4 * 4 + 2) * D + lane], acc2);
        acc2 = fmaf(h4.w, W[(k4 * 4 + 3) * D + lane], acc2);
    }

    // LayerNorm across the 64 lanes
    float s = acc2;
    for (int m = 32; m; m >>= 1) s += __shfl_xor(s, m, 64);
    float mu = s * (1.f / 64.f);
    float dv = acc2 - mu;
    float v2 = dv * dv;
    for (int m = 32; m; m >>= 1) v2 += __shfl_xor(v2, m, 64);
    float var = v2 * (1.f / 64.f);
    float res = dv * rsqrtf(var + LN_EPS) * gg[lane] + be[lane];

    if (LAYER == 0)
        outb[(unsigned)(node * D) + lane] = f2b(res);
    else
        __builtin_nontemporal_store(res, outf + (unsigned)(node * D) + lane);
}

extern "C" void kernel_launch(void* const* d_in, const int* in_sizes, int n_in,
                              void* d_out, int out_size, void* d_ws, size_t ws_size,
                              hipStream_t stream) {
    const float* node_attr = (const float*)d_in[0];
    const int* edge_index = (const int*)d_in[1];
    // d_in[2] = batch_idx (unused)
    const float* adv0 = (const float*)d_in[3];
    const float* adv1 = (const float*)d_in[4];
    const float* W0 = (const float*)d_in[5];
    const float* b0 = (const float*)d_in[6];
    const float* g0 = (const float*)d_in[7];
    const float* be0 = (const float*)d_in[8];
    const float* W1 = (const float*)d_in[9];
    const float* b1 = (const float*)d_in[10];
    const float* g1 = (const float*)d_in[11];
    const float* be1 = (const float*)d_in[12];

    const int* src = edge_index;            // edge_index[0]
    const int* dst = edge_index + N_EDGES;  // edge_index[1]

    // workspace layout (~39 MB)
    v2i* rec = (v2i*)d_ws;                                   // [E] 12.8 MB {src, advs}
    unsigned short* xb0 = (unsigned short*)(rec + N_EDGES);  // [N*D] bf16 12.8 MB
    unsigned short* h1b = xb0 + (size_t)N_NODES * D;         // [N*D] bf16 12.8 MB
    int* offsets = (int*)(h1b + (size_t)N_NODES * D);        // [N+1]
    int* cursor = offsets + (N_NODES + 1);                   // [N]
    int* counts = cursor + N_NODES;                          // [N]
    int* blockSums = counts + N_NODES;                       // [512]

    float* out = (float*)d_out;

    // ---- node_attr -> bf16 + zero counts ----
    k_tobf16z<<<3125, 256, 0, stream>>>((const float4*)node_attr, (uint4*)xb0, counts);

    // ---- build CSR by dst (once; serves both layers) ----
    k_hist<<<N_EDGES / 256, 256, 0, stream>>>(dst, counts);
    k_scan1<<<SCAN_NB, 256, 0, stream>>>(counts, offsets, blockSums);
    k_scan2<<<1, 512, 0, stream>>>(blockSums);
    k_scan3<<<SCAN_NB, 256, 0, stream>>>(offsets, blockSums, cursor);
    k_bucket<<<N_EDGES / 256, 256, 0, stream>>>(src, dst, adv0, adv1, cursor, rec);

    // ---- layer 1: gather xb0, residual node_attr(f32) -> h1b (bf16) ----
    k_layer<0><<<N_NODES / 4, 256, 0, stream>>>(node_attr, xb0, rec, offsets,
                                                W0, b0, g0, be0, nullptr, h1b);
    // ---- layer 2: gather h1b, residual h1b -> out (f32) ----
    k_layer<1><<<N_NODES / 4, 256, 0, stream>>>(nullptr, h1b, rec, offsets,
                                                W1, b1, g1, be1, out, nullptr);
}

// Round 9
// 331.234 us; speedup vs baseline: 1.2537x; 1.0951x over previous
//
#include <hip/hip_runtime.h>
#include <math.h>

#define N_NODES 100000
#define N_EDGES 1600000
#define D 64
#define LN_EPS 1e-5f
#define SCAN_NB 391    // ceil(100000/256)
#define NODE_RANGE 12500  // N_NODES / 8 (dst range per XCD group)

typedef int v2i __attribute__((ext_vector_type(2)));

// ---- bf16 helpers (RNE) ----
__device__ __forceinline__ unsigned short f2b(float f) {
    unsigned u = __float_as_uint(f);
    return (unsigned short)((u + 0x7FFFu + ((u >> 16) & 1u)) >> 16);
}
__device__ __forceinline__ unsigned pk2(float lo, float hi) {
    return (unsigned)f2b(lo) | ((unsigned)f2b(hi) << 16);
}
__device__ __forceinline__ float b2f(unsigned short u) {
    return __uint_as_float((unsigned)u << 16);
}

// ---------------- f32 -> bf16 row conversion (8 elems/thread) + zero counts ----------------
__global__ void k_tobf16z(const float4* __restrict__ in4, uint4* __restrict__ out4,
                          int* __restrict__ counts) {
    int i = blockIdx.x * 256 + threadIdx.x;  // 3125*256 == N*D/8 exactly
    if (i < N_NODES) counts[i] = 0;
    float4 a = in4[2 * i];
    float4 c = in4[2 * i + 1];
    uint4 o;
    o.x = pk2(a.x, a.y);
    o.y = pk2(a.z, a.w);
    o.z = pk2(c.x, c.y);
    o.w = pk2(c.z, c.w);
    out4[i] = o;
}

// ---------------- histogram of dst, XCD-grouped ----------------
// group g = blockIdx&7 (~XCD id) handles dst in [g*NODE_RANGE, (g+1)*NODE_RANGE):
// atomics on counts become XCD-local -> no cross-XCD line ping-pong.
__global__ void k_hist(const int* __restrict__ dst, int* __restrict__ counts) {
    const int g = blockIdx.x & 7;
    const int lb = blockIdx.x >> 3;
    const int nlb = gridDim.x >> 3;
    const int lo = g * NODE_RANGE, hi = lo + NODE_RANGE;
    for (int e = lb * 256 + threadIdx.x; e < N_EDGES; e += nlb * 256) {
        int d = __builtin_nontemporal_load(dst + e);
        if (d >= lo && d < hi) atomicAdd(&counts[d], 1);
    }
}

// ---------------- scan step 1: per-block exclusive scan + block sums ----------------
__global__ void k_scan1(const int* __restrict__ counts, int* __restrict__ offsets,
                        int* __restrict__ blockSums) {
    __shared__ int s[256];
    int tid = threadIdx.x;
    int i = blockIdx.x * 256 + tid;
    int v = (i < N_NODES) ? counts[i] : 0;
    s[tid] = v;
    __syncthreads();
    for (int off = 1; off < 256; off <<= 1) {
        int t = (tid >= off) ? s[tid - off] : 0;
        __syncthreads();
        s[tid] += t;
        __syncthreads();
    }
    if (i < N_NODES) offsets[i] = s[tid] - v;  // exclusive within block
    if (tid == 255) blockSums[blockIdx.x] = s[255];
}

// ---------------- scan step 2: exclusive scan of block sums (single block) ----------------
__global__ void k_scan2(int* __restrict__ blockSums) {
    __shared__ int s[512];
    int tid = threadIdx.x;
    int v = (tid < SCAN_NB) ? blockSums[tid] : 0;
    s[tid] = v;
    __syncthreads();
    for (int off = 1; off < 512; off <<= 1) {
        int t = (tid >= off) ? s[tid - off] : 0;
        __syncthreads();
        s[tid] += t;
        __syncthreads();
    }
    if (tid < SCAN_NB) blockSums[tid] = s[tid] - v;  // exclusive
}

// ---------------- scan step 3: add block offsets; init cursor ----------------
__global__ void k_scan3(int* __restrict__ offsets, const int* __restrict__ blockSums,
                        int* __restrict__ cursor) {
    int i = blockIdx.x * 256 + threadIdx.x;
    if (i < N_NODES) {
        int o = offsets[i] + blockSums[blockIdx.x];
        offsets[i] = o;
        cursor[i] = o;
    }
    if (i == 0) offsets[N_NODES] = N_EDGES;
}

// ---------------- bucket edges into CSR order, XCD-grouped ----------------
// rec = {src, bf16(adv0)|bf16(adv1)<<16}. Group g writes only the CSR region for
// its dst range -> stores + cursor atomics stay XCD-local, lines written back once.
__global__ void k_bucket(const int* __restrict__ src, const int* __restrict__ dst,
                         const float* __restrict__ adv0, const float* __restrict__ adv1,
                         int* __restrict__ cursor, v2i* __restrict__ rec) {
    const int g = blockIdx.x & 7;
    const int lb = blockIdx.x >> 3;
    const int nlb = gridDim.x >> 3;
    const int lo = g * NODE_RANGE, hi = lo + NODE_RANGE;
    for (int e = lb * 256 + threadIdx.x; e < N_EDGES; e += nlb * 256) {
        int d = __builtin_nontemporal_load(dst + e);
        if (d >= lo && d < hi) {
            int s = __builtin_nontemporal_load(src + e);
            float a0 = __builtin_nontemporal_load(adv0 + e);
            float a1 = __builtin_nontemporal_load(adv1 + e);
            int p = atomicAdd(&cursor[d], 1);
            v2i r;
            r.x = s;
            r.y = (int)pk2(a0, a1);
            rec[p] = r;
        }
    }
}

// ---------------- fused layer: gather-aggregate(bf16) + gelu/res + matvec + LN ----------------
// LAYER==0: residual from xres(f32), adv=lo16(rec.y), output -> outb (bf16)
// LAYER==1: residual from xb(bf16),  adv=hi16(rec.y), output -> outf (f32)
template <int LAYER>
__global__ __launch_bounds__(256) void k_layer(const float* __restrict__ xres,
                                               const unsigned short* __restrict__ xb,
                                               const v2i* __restrict__ rec,
                                               const int* __restrict__ offsets,
                                               const float* __restrict__ W,
                                               const float* __restrict__ bb,
                                               const float* __restrict__ gg,
                                               const float* __restrict__ be,
                                               float* __restrict__ outf,
                                               unsigned short* __restrict__ outb) {
    const int lane = threadIdx.x & 63;
    const int wid = threadIdx.x >> 6;       // 4 waves/block, one node each
    const int node = blockIdx.x * 4 + wid;  // 25000*4 == N_NODES exactly
    const int beg = offsets[node];
    const int end = offsets[node + 1];

    float acc0 = 0.f, acc1 = 0.f, acc2a = 0.f, acc3a = 0.f, sadv = 0.f;
    for (int cb = beg; cb < end; cb += 64) {
        const int n = min(64, end - cb);
        int sv = 0, avi = 0;
        if (lane < n) {
            v2i r = __builtin_nontemporal_load(rec + cb + lane);
            sv = r.x;
            unsigned pa = (unsigned)r.y;
            avi = (int)(LAYER ? (pa & 0xFFFF0000u) : (pa << 16));  // f32 bits of adv
        }
        sadv += __int_as_float(avi);  // masked lanes add 0
        int k = 0;
        for (; k + 8 <= n; k += 8) {
            int s0 = __builtin_amdgcn_readlane(sv, k);
            int s1 = __builtin_amdgcn_readlane(sv, k + 1);
            int s2 = __builtin_amdgcn_readlane(sv, k + 2);
            int s3 = __builtin_amdgcn_readlane(sv, k + 3);
            int s4 = __builtin_amdgcn_readlane(sv, k + 4);
            int s5 = __builtin_amdgcn_readlane(sv, k + 5);
            int s6 = __builtin_amdgcn_readlane(sv, k + 6);
            int s7 = __builtin_amdgcn_readlane(sv, k + 7);
            float x0 = b2f(xb[(unsigned)(s0 * D) + lane]);
            float x1 = b2f(xb[(unsigned)(s1 * D) + lane]);
            float x2 = b2f(xb[(unsigned)(s2 * D) + lane]);
            float x3 = b2f(xb[(unsigned)(s3 * D) + lane]);
            float x4 = b2f(xb[(unsigned)(s4 * D) + lane]);
            float x5 = b2f(xb[(unsigned)(s5 * D) + lane]);
            float x6 = b2f(xb[(unsigned)(s6 * D) + lane]);
            float x7 = b2f(xb[(unsigned)(s7 * D) + lane]);
            float a0 = __int_as_float(__builtin_amdgcn_readlane(avi, k));
            float a1 = __int_as_float(__builtin_amdgcn_readlane(avi, k + 1));
            float a2 = __int_as_float(__builtin_amdgcn_readlane(avi, k + 2));
            float a3 = __int_as_float(__builtin_amdgcn_readlane(avi, k + 3));
            float a4 = __int_as_float(__builtin_amdgcn_readlane(avi, k + 4));
            float a5 = __int_as_float(__builtin_amdgcn_readlane(avi, k + 5));
            float a6 = __int_as_float(__builtin_amdgcn_readlane(avi, k + 6));
            float a7 = __int_as_float(__builtin_amdgcn_readlane(avi, k + 7));
            acc0 = fmaf(x0, a0, acc0);
            acc1 = fmaf(x1, a1, acc1);
            acc2a = fmaf(x2, a2, acc2a);
            acc3a = fmaf(x3, a3, acc3a);
            acc0 = fmaf(x4, a4, acc0);
            acc1 = fmaf(x5, a5, acc1);
            acc2a = fmaf(x6, a6, acc2a);
            acc3a = fmaf(x7, a7, acc3a);
        }
        for (; k + 4 <= n; k += 4) {
            int s0 = __builtin_amdgcn_readlane(sv, k);
            int s1 = __builtin_amdgcn_readlane(sv, k + 1);
            int s2 = __builtin_amdgcn_readlane(sv, k + 2);
            int s3 = __builtin_amdgcn_readlane(sv, k + 3);
            float x0 = b2f(xb[(unsigned)(s0 * D) + lane]);
            float x1 = b2f(xb[(unsigned)(s1 * D) + lane]);
            float x2 = b2f(xb[(unsigned)(s2 * D) + lane]);
            float x3 = b2f(xb[(unsigned)(s3 * D) + lane]);
            float a0 = __int_as_float(__builtin_amdgcn_readlane(avi, k));
            float a1 = __int_as_float(__builtin_amdgcn_readlane(avi, k + 1));
            float a2 = __int_as_float(__builtin_amdgcn_readlane(avi, k + 2));
            float a3 = __int_as_float(__builtin_amdgcn_readlane(avi, k + 3));
            acc0 = fmaf(x0, a0, acc0);
            acc1 = fmaf(x1, a1, acc1);
            acc2a = fmaf(x2, a2, acc2a);
            acc3a = fmaf(x3, a3, acc3a);
        }
        for (; k < n; ++k) {
            int s0 = __builtin_amdgcn_readlane(sv, k);
            float a0 = __int_as_float(__builtin_amdgcn_readlane(avi, k));
            acc0 = fmaf(b2f(xb[(unsigned)(s0 * D) + lane]), a0, acc0);
        }
    }
    for (int m = 32; m; m >>= 1) sadv += __shfl_xor(sadv, m, 64);
    float acc = (acc0 + acc1) + (acc2a + acc3a);
    float aggr = (end > beg) ? acc / sadv : 0.f;

    float xv = (LAYER == 0) ? xres[(unsigned)(node * D) + lane]
                            : b2f(xb[(unsigned)(node * D) + lane]);
    // exact GELU: 0.5*a + 0.5*a*erf(a/sqrt(2)), plus residual
    float ge = 0.5f * aggr;
    float h = fmaf(ge, erff(aggr * 0.70710678118654752f), ge + xv);

    // wave-private LDS transpose; same-wave write/read (no barrier needed)
    __shared__ float hs[4][D];
    hs[wid][lane] = h;
    float acc2 = bb[lane];
    const float4* h4p = (const float4*)(&hs[wid][0]);
#pragma unroll
    for (int k4 = 0; k4 < 16; ++k4) {
        float4 h4 = h4p[k4];
        acc2 = fmaf(h4.x, W[(k4 * 4 + 0) * D + lane], acc2);
        acc2 = fmaf(h4.y, W[(k4 * 4 + 1) * D + lane], acc2);
        acc2 = fmaf(h4.z, W[(k4 * 4 + 2) * D + lane], acc2);
        acc2 = fmaf(h4.w, W[(k4 * 4 + 3) * D + lane], acc2);
    }

    // LayerNorm across the 64 lanes
    float s = acc2;
    for (int m = 32; m; m >>= 1) s += __shfl_xor(s, m, 64);
    float mu = s * (1.f / 64.f);
    float dv = acc2 - mu;
    float v2 = dv * dv;
    for (int m = 32; m; m >>= 1) v2 += __shfl_xor(v2, m, 64);
    float var = v2 * (1.f / 64.f);
    float res = dv * rsqrtf(var + LN_EPS) * gg[lane] + be[lane];

    if (LAYER == 0)
        outb[(unsigned)(node * D) + lane] = f2b(res);
    else
        __builtin_nontemporal_store(res, outf + (unsigned)(node * D) + lane);
}

extern "C" void kernel_launch(void* const* d_in, const int* in_sizes, int n_in,
                              void* d_out, int out_size, void* d_ws, size_t ws_size,
                              hipStream_t stream) {
    const float* node_attr = (const float*)d_in[0];
    const int* edge_index = (const int*)d_in[1];
    // d_in[2] = batch_idx (unused)
    const float* adv0 = (const float*)d_in[3];
    const float* adv1 = (const float*)d_in[4];
    const float* W0 = (const float*)d_in[5];
    const float* b0 = (const float*)d_in[6];
    const float* g0 = (const float*)d_in[7];
    const float* be0 = (const float*)d_in[8];
    const float* W1 = (const float*)d_in[9];
    const float* b1 = (const float*)d_in[10];
    const float* g1 = (const float*)d_in[11];
    const float* be1 = (const float*)d_in[12];

    const int* src = edge_index;            // edge_index[0]
    const int* dst = edge_index + N_EDGES;  // edge_index[1]

    // workspace layout (~39 MB)
    v2i* rec = (v2i*)d_ws;                                   // [E] 12.8 MB {src, advs}
    unsigned short* xb0 = (unsigned short*)(rec + N_EDGES);  // [N*D] bf16 12.8 MB
    unsigned short* h1b = xb0 + (size_t)N_NODES * D;         // [N*D] bf16 12.8 MB
    int* offsets = (int*)(h1b + (size_t)N_NODES * D);        // [N+1]
    int* cursor = offsets + (N_NODES + 1);                   // [N]
    int* counts = cursor + N_NODES;                          // [N]
    int* blockSums = counts + N_NODES;                       // [512]

    float* out = (float*)d_out;

    // ---- node_attr -> bf16 + zero counts ----
    k_tobf16z<<<3125, 256, 0, stream>>>((const float4*)node_attr, (uint4*)xb0, counts);

    // ---- build CSR by dst (once; serves both layers), XCD-grouped scatter ----
    k_hist<<<2048, 256, 0, stream>>>(dst, counts);
    k_scan1<<<SCAN_NB, 256, 0, stream>>>(counts, offsets, blockSums);
    k_scan2<<<1, 512, 0, stream>>>(blockSums);
    k_scan3<<<SCAN_NB, 256, 0, stream>>>(offsets, blockSums, cursor);
    k_bucket<<<2048, 256, 0, stream>>>(src, dst, adv0, adv1, cursor, rec);

    // ---- layer 1: gather xb0, residual node_attr(f32) -> h1b (bf16) ----
    k_layer<0><<<N_NODES / 4, 256, 0, stream>>>(node_attr, xb0, rec, offsets,
                                                W0, b0, g0, be0, nullptr, h1b);
    // ---- layer 2: gather h1b, residual h1b -> out (f32) ----
    k_layer<1><<<N_NODES / 4, 256, 0, stream>>>(nullptr, h1b, rec, offsets,
                                                W1, b1, g1, be1, out, nullptr);
}